// Round 2
// baseline (302.299 us; speedup 1.0000x reference)
//
#include <hip/hip_runtime.h>
#include <hip/hip_bf16.h>

typedef _Float16 f16;
typedef _Float16 f16x4 __attribute__((ext_vector_type(4)));
typedef _Float16 f16x8 __attribute__((ext_vector_type(8)));
typedef float f32x4 __attribute__((ext_vector_type(4)));

#define S_LEN 4096
#define DIM   512
#define NH    8
#define DH    64
#define BATCH 2
#define BHDIM (BATCH*NH)   // 16

// Q pre-scale: 1/sqrt(64) * log2(e)  (softmax done in exp2 domain)
#define QSCALE 0.18033688011112042f

__device__ __forceinline__ void gld16(const f16* g, f16* l) {
#if __has_builtin(__builtin_amdgcn_global_load_lds)
  __builtin_amdgcn_global_load_lds((const __attribute__((address_space(1))) void*)g,
                                   (__attribute__((address_space(3))) void*)l, 16, 0, 0);
#else
  *(f16x8*)l = *(const f16x8*)g;
#endif
}

// ---------------- RMSNorm: x[8192,512] f32 -> xn f16 ----------------
__global__ __launch_bounds__(256) void rmsnorm_kernel(
    const float* __restrict__ x, const float* __restrict__ scale,
    f16* __restrict__ xn) {
  int row = blockIdx.x;
  int tid = threadIdx.x;
  const float* xr = x + (size_t)row * DIM;
  float2 v = *(const float2*)(xr + tid*2);
  float ss = v.x*v.x + v.y*v.y;
  #pragma unroll
  for (int off = 32; off > 0; off >>= 1) ss += __shfl_down(ss, off);
  __shared__ float red[4];
  if ((tid & 63) == 0) red[tid >> 6] = ss;
  __syncthreads();
  float tot = red[0] + red[1] + red[2] + red[3];
  float inv = rsqrtf(tot * (1.0f/DIM) + 1e-6f);
  float2 s = *(const float2*)(scale + tid*2);
  xn[(size_t)row*DIM + tid*2+0] = (f16)(v.x*inv*s.x);
  xn[(size_t)row*DIM + tid*2+1] = (f16)(v.y*inv*s.y);
}

// ------------- Transpose+convert weights: W[k][n] f32 -> Wt[n][k] f16 -------------
__global__ void transpose_kernel(const float* __restrict__ Wq,
                                 const float* __restrict__ Wk,
                                 const float* __restrict__ Wv,
                                 const float* __restrict__ Wo,
                                 f16* __restrict__ wt_qkv, f16* __restrict__ wo_t) {
  __shared__ f16 tile[32][33];
  int mat = blockIdx.z;
  const float* src = (mat == 0) ? Wq : (mat == 1) ? Wk : (mat == 2) ? Wv : Wo;
  f16* dst = (mat < 3) ? (wt_qkv + (size_t)mat*DIM*DIM) : wo_t;
  int k0 = blockIdx.y * 32, n0 = blockIdx.x * 32;
  int tx = threadIdx.x, ty = threadIdx.y;  // (32, 8)
  #pragma unroll
  for (int i = 0; i < 32; i += 8)
    tile[ty+i][tx] = (f16)src[(size_t)(k0+ty+i)*DIM + n0+tx];
  __syncthreads();
  #pragma unroll
  for (int i = 0; i < 32; i += 8)
    dst[(size_t)(n0+ty+i)*DIM + k0+tx] = tile[tx][ty+i];
}

// ------------- RoPE cos/sin tables: [4096][32] f32 -------------
__global__ __launch_bounds__(256) void rope_table_kernel(float* __restrict__ ctab,
                                                         float* __restrict__ stab) {
  int idx = blockIdx.x*256 + threadIdx.x;   // 0..131071
  int t = idx >> 5, d = idx & 31;
  float theta = exp2f(-(float)d * (19.931568569324174f / 32.0f));
  float sv, cv;
  sincosf((float)t * theta, &sv, &cv);
  ctab[idx] = cv; stab[idx] = sv;
}

// ------------- m97-style 128x128 GEMM core: C = A[M,512] * Bt[N,512]^T -------------
__device__ __forceinline__ void gemm128_acc(
    const f16* __restrict__ A, const f16* __restrict__ Bt,
    int m0, int n0, f16* As, f16* Bs, f32x4 (&acc)[4][4]) {
  const int tid = threadIdx.x;
  const int wave = tid >> 6, lane = tid & 63;
  const int l16 = lane & 15, quad = lane >> 4;
  const int mrow = (wave & 1) * 64, ncol = (wave >> 1) * 64;
  const int srow = tid >> 3;                    // 0..31
  const int gc = (tid & 7) ^ ((tid >> 3) & 7);  // swizzled source chunk

  for (int k0 = 0; k0 < DIM; k0 += 64) {
    if (k0) __syncthreads();
    #pragma unroll
    for (int i = 0; i < 4; i++) {
      gld16(A  + (size_t)(m0 + i*32 + srow)*DIM + k0 + gc*8, As + i*2048 + tid*8);
      gld16(Bt + (size_t)(n0 + i*32 + srow)*DIM + k0 + gc*8, Bs + i*2048 + tid*8);
    }
    __syncthreads();
    #pragma unroll
    for (int kc = 0; kc < 2; kc++) {
      f16x8 a[4], b[4];
      #pragma unroll
      for (int mt = 0; mt < 4; mt++) {
        int row = mrow + mt*16 + l16;
        a[mt] = *(const f16x8*)(As + row*64 + (((quad + 4*kc) ^ (l16 & 7)) * 8));
      }
      #pragma unroll
      for (int nt = 0; nt < 4; nt++) {
        int row = ncol + nt*16 + l16;
        b[nt] = *(const f16x8*)(Bs + row*64 + (((quad + 4*kc) ^ (l16 & 7)) * 8));
      }
      #pragma unroll
      for (int mt = 0; mt < 4; mt++)
        #pragma unroll
        for (int nt = 0; nt < 4; nt++)
          acc[mt][nt] = __builtin_amdgcn_mfma_f32_16x16x32_f16(a[mt], b[nt], acc[mt][nt], 0, 0, 0);
    }
  }
}

// ------------- QKV GEMM + table-RoPE + Q prescale -------------
__global__ __launch_bounds__(256) void qkv_gemm_kernel(
    const f16* __restrict__ xn, const f16* __restrict__ wt,
    const float* __restrict__ ctab, const float* __restrict__ stab,
    f16* __restrict__ qbuf, f16* __restrict__ kbuf, f16* __restrict__ vt) {
  __shared__ __align__(16) f16 As[128*64], Bs[128*64];
  int m0 = blockIdx.x * 128, n0 = blockIdx.y * 128;
  f32x4 acc[4][4] = {};
  gemm128_acc(xn, wt, m0, n0, As, Bs, acc);

  const int tid = threadIdx.x;
  const int wave = tid >> 6, lane = tid & 63;
  const int l16 = lane & 15, quad = lane >> 4;
  int ncol = n0 + (wave >> 1) * 64;      // head-aligned
  int which = ncol >> 9;                 // 0=q 1=k 2=v (wave-uniform)
  int head = (ncol >> 6) & 7;
  int mbase = m0 + (wave & 1) * 64;

  if (which <= 1) {                      // fused RoPE from tables
    #pragma unroll
    for (int mt = 0; mt < 4; mt++)
      #pragma unroll
      for (int nt = 0; nt < 2; nt++) {
        int d = nt*16 + l16;
        #pragma unroll
        for (int r = 0; r < 4; r++) {
          int t = (mbase + mt*16 + quad*4 + r) & 4095;
          float cv = ctab[t*32 + d], sv = stab[t*32 + d];
          float x1 = acc[mt][nt][r], x2 = acc[mt][nt+2][r];
          acc[mt][nt][r]   = x1*cv - x2*sv;
          acc[mt][nt+2][r] = x1*sv + x2*cv;
        }
      }
  }
  if (which < 2) {
    float osc = (which == 0) ? QSCALE : 1.0f;
    f16* dst = which ? kbuf : qbuf;
    #pragma unroll
    for (int mt = 0; mt < 4; mt++)
      #pragma unroll
      for (int nt = 0; nt < 4; nt++)
        #pragma unroll
        for (int r = 0; r < 4; r++) {
          int m = mbase + mt*16 + quad*4 + r;
          int b = m >> 12, t = m & 4095;
          dst[(((size_t)(b*NH + head))*S_LEN + t)*DH + nt*16 + l16] = (f16)(acc[mt][nt][r]*osc);
        }
  } else {                               // V transposed, pack 4 consecutive tokens
    #pragma unroll
    for (int mt = 0; mt < 4; mt++)
      #pragma unroll
      for (int nt = 0; nt < 4; nt++) {
        int m = mbase + mt*16 + quad*4;
        int b = m >> 12, t = m & 4095;
        int d = nt*16 + l16;
        f16x4 v4 = {(f16)acc[mt][nt][0], (f16)acc[mt][nt][1],
                    (f16)acc[mt][nt][2], (f16)acc[mt][nt][3]};
        *(f16x4*)(vt + ((size_t)((b*NH + head)*DH + d))*S_LEN + t) = v4;
      }
  }
}

// ------------- Flash attention (causal), barrier-free 1-wave blocks -------------
// 2048 blocks x 64 threads; each wave owns 32 q-rows, reads K/V fragments
// straight from L2-resident global buffers (no K/V LDS staging, no barriers).
// Block id layout: bid = g*64 + band*16 + bh  ->  bid&7 == bh&7 (XCD/L2 locality).
// qtb(g) is a boustrophedon table: per-CU tile counts are exactly equal and
// heavy q-tiles dispatch first.
__global__ __launch_bounds__(64, 2) void attn_kernel(
    const f16* __restrict__ qbuf, const f16* __restrict__ kbuf,
    const f16* __restrict__ vtb, f16* __restrict__ ao) {
  int bid = blockIdx.x;                  // 0..2047
  int bh   = bid & 15;
  int band = (bid >> 4) & 3;             // 32-row band within the 128-row q-tile
  int g    = bid >> 6;                   // 0..31
  int r8 = g >> 2, j4 = g & 3;
  int qtb = (r8 & 1) ? (28 - 4*r8 + j4) : (31 - 4*r8 - j4);

  int lane = threadIdx.x;                // one wave per block
  int l16 = lane & 15, quad = lane >> 4;

  const f16* Q = qbuf + (size_t)bh*S_LEN*DH;
  const f16* K = kbuf + (size_t)bh*S_LEN*DH;
  const f16* V = vtb  + (size_t)bh*DH*S_LEN;   // [dh][s]

  int rw = qtb*128 + band*32;

  // Q fragments (B-operand of S^T = K Q^T)
  f16x8 qa[2][2];
  #pragma unroll
  for (int mf = 0; mf < 2; mf++) {
    const f16* qrow = Q + (size_t)(rw + mf*16 + l16)*DH + quad*8;
    qa[mf][0] = *(const f16x8*)(qrow);
    qa[mf][1] = *(const f16x8*)(qrow + 32);
  }

  f32x4 o[2][4] = {};                    // O C-layout [qrow=quad*4+r][dh=dnt*16+l16]
  float m_i[2] = {-1e30f, -1e30f};       // per-lane state for qrow = l16 (replicated over quads)
  float l_i[2] = {0.f, 0.f};

  // per-wave swizzled P buffer, one region per mf (both read back in one V pass)
  __shared__ __align__(16) f16 pls[2*16*128];  // 8 KB

  int ntiles = qtb + 1;
  int ntl = 2*band + 2;   // live S^T fragments on the diagonal tile (uniform)
  int kcl = band + 1;     // live PV key-blocks on the diagonal tile (uniform)

  for (int it = 0; it < ntiles; ++it) {
    int kv0 = it * 128;
    bool last = (it == ntiles - 1);

    // ---- S^T = K Q^T : C-layout row=key_local quad*4+r, col=qrow_local l16 ----
    f32x4 st[2][8];
    #pragma unroll
    for (int nt = 0; nt < 8; nt++) {
      if (!(last && nt >= ntl)) {
        const f16* krow = K + (size_t)(kv0 + nt*16 + l16)*DH + quad*8;
        f16x8 kf0 = *(const f16x8*)(krow);
        f16x8 kf1 = *(const f16x8*)(krow + 32);
        f32x4 z0 = {}, z1 = {};
        z0 = __builtin_amdgcn_mfma_f32_16x16x32_f16(kf0, qa[0][0], z0, 0, 0, 0);
        z1 = __builtin_amdgcn_mfma_f32_16x16x32_f16(kf0, qa[1][0], z1, 0, 0, 0);
        st[0][nt] = __builtin_amdgcn_mfma_f32_16x16x32_f16(kf1, qa[0][1], z0, 0, 0, 0);
        st[1][nt] = __builtin_amdgcn_mfma_f32_16x16x32_f16(kf1, qa[1][1], z1, 0, 0, 0);
      }
    }

    #pragma unroll
    for (int mf = 0; mf < 2; mf++) {
      int qrow = rw + mf*16 + l16;
      float rmx = -1e30f;
      if (last) {                        // diagonal tile: causal mask (live frags only)
        #pragma unroll
        for (int nt = 0; nt < 8; nt++) {
          if (nt >= ntl) continue;
          int kbase = kv0 + nt*16 + quad*4;
          #pragma unroll
          for (int r = 0; r < 4; r++) {
            float v = st[mf][nt][r];
            if (kbase + r > qrow) v = -1e30f;
            st[mf][nt][r] = v;
            rmx = fmaxf(rmx, v);
          }
        }
      } else {
        #pragma unroll
        for (int nt = 0; nt < 8; nt++)
          #pragma unroll
          for (int r = 0; r < 4; r++) rmx = fmaxf(rmx, st[mf][nt][r]);
      }
      rmx = fmaxf(rmx, __shfl_xor(rmx, 16));
      rmx = fmaxf(rmx, __shfl_xor(rmx, 32));
      // defer-max (T13): skip O-rescale while the running max is within THR=8
      float mnew = fmaxf(m_i[mf], rmx);
      if (!__all(rmx <= m_i[mf] + 8.0f)) {
        float alpha = exp2f(m_i[mf] - mnew);
        m_i[mf] = mnew;
        float al[4];
        #pragma unroll
        for (int r = 0; r < 4; r++) al[r] = __shfl(alpha, quad*4 + r);
        #pragma unroll
        for (int dnt = 0; dnt < 4; dnt++)
          #pragma unroll
          for (int r = 0; r < 4; r++) o[mf][dnt][r] *= al[r];
        l_i[mf] *= alpha;
      }
      float mref = m_i[mf];
      // P = exp2(st - mref) (bounded by 2^THR), pack f16x4, store to pls[mf]
      float rs = 0.f;
      f16* plw = pls + mf*2048 + l16*128;
      #pragma unroll
      for (int nt = 0; nt < 8; nt++) {
        f16x4 p4 = {};
        if (!(last && nt >= ntl)) {
          #pragma unroll
          for (int r = 0; r < 4; r++) {
            float p = exp2f(st[mf][nt][r] - mref);
            rs += p;
            p4[r] = (f16)p;
          }
        }
        int cw = nt*2 + (quad >> 1);
        *(f16x4*)(plw + ((cw ^ (l16 & 7))*8) + (quad & 1)*4) = p4;
      }
      rs += __shfl_xor(rs, 16);
      rs += __shfl_xor(rs, 32);
      l_i[mf] += rs;
    }

    // ---- PV: single V pass, both mf halves per fragment ----
    #pragma unroll
    for (int kc = 0; kc < 4; kc++) {
      if (last && kc >= kcl) continue;
      f16x8 pa0 = *(const f16x8*)(pls +        l16*128 + (((kc*4 + quad) ^ (l16 & 7))*8));
      f16x8 pa1 = *(const f16x8*)(pls + 2048 + l16*128 + (((kc*4 + quad) ^ (l16 & 7))*8));
      #pragma unroll
      for (int dnt = 0; dnt < 4; dnt++) {
        const f16* vrow = V + (size_t)(dnt*16 + l16)*S_LEN + kv0 + kc*32 + quad*8;
        f16x8 vf = *(const f16x8*)vrow;
        o[0][dnt] = __builtin_amdgcn_mfma_f32_16x16x32_f16(pa0, vf, o[0][dnt], 0, 0, 0);
        o[1][dnt] = __builtin_amdgcn_mfma_f32_16x16x32_f16(pa1, vf, o[1][dnt], 0, 0, 0);
      }
    }
  }

  // epilogue
  int b = bh >> 3, h = bh & 7;
  #pragma unroll
  for (int mf = 0; mf < 2; mf++) {
    float lr[4];
    #pragma unroll
    for (int r = 0; r < 4; r++) lr[r] = __shfl(l_i[mf], quad*4 + r);
    #pragma unroll
    for (int r = 0; r < 4; r++) {
      float invl = 1.0f / lr[r];
      int t = rw + mf*16 + quad*4 + r;
      size_t rowoff = ((size_t)(b*S_LEN + t))*DIM + h*DH;
      #pragma unroll
      for (int dnt = 0; dnt < 4; dnt++)
        ao[rowoff + dnt*16 + l16] = (f16)(o[mf][dnt][r]*invl);
    }
  }
}

// ------------- Output GEMM: ao[8192,512] @ Wo -> out f32 -------------
__global__ __launch_bounds__(256) void out_gemm_kernel(
    const f16* __restrict__ ao, const f16* __restrict__ wot,
    float* __restrict__ out) {
  __shared__ __align__(16) f16 As[128*64], Bs[128*64];
  int m0 = blockIdx.x * 128, n0 = blockIdx.y * 128;
  f32x4 acc[4][4] = {};
  gemm128_acc(ao, wot, m0, n0, As, Bs, acc);

  const int tid = threadIdx.x;
  const int wave = tid >> 6, lane = tid & 63;
  const int l16 = lane & 15, quad = lane >> 4;
  int ncol = n0 + (wave >> 1) * 64;
  int mbase = m0 + (wave & 1) * 64;
  #pragma unroll
  for (int mt = 0; mt < 4; mt++)
    #pragma unroll
    for (int nt = 0; nt < 4; nt++)
      #pragma unroll
      for (int r = 0; r < 4; r++)
        out[(size_t)(mbase + mt*16 + quad*4 + r)*DIM + ncol + nt*16 + l16] = acc[mt][nt][r];
}

extern "C" void kernel_launch(void* const* d_in, const int* in_sizes, int n_in,
                              void* d_out, int out_size, void* d_ws, size_t ws_size,
                              hipStream_t stream) {
  const float* x     = (const float*)d_in[0];
  const float* scale = (const float*)d_in[1];
  const float* Wq    = (const float*)d_in[2];
  const float* Wk    = (const float*)d_in[3];
  const float* Wv    = (const float*)d_in[4];
  const float* Wo    = (const float*)d_in[5];
  float* out = (float*)d_out;

  const size_t ROWS = (size_t)BATCH * S_LEN;   // 8192
  char* ws = (char*)d_ws;
  f16* xn     = (f16*)ws;  ws += ROWS * DIM * sizeof(f16);            // 8 MB (reused as ao)
  f16* wt_qkv = (f16*)ws;  ws += (size_t)3 * DIM * DIM * sizeof(f16); // 1.5 MB
  f16* wo_t   = (f16*)ws;  ws += (size_t)DIM * DIM * sizeof(f16);     // 0.5 MB
  f16* qb     = (f16*)ws;  ws += (size_t)BHDIM * S_LEN * DH * sizeof(f16); // 8 MB
  f16* kb     = (f16*)ws;  ws += (size_t)BHDIM * S_LEN * DH * sizeof(f16); // 8 MB
  f16* vt     = (f16*)ws;  ws += (size_t)BHDIM * S_LEN * DH * sizeof(f16); // 8 MB
  float* ctab = (float*)ws; ws += (size_t)S_LEN * 32 * sizeof(float);  // 0.5 MB
  float* stab = (float*)ws; ws += (size_t)S_LEN * 32 * sizeof(float);  // 0.5 MB
  f16* ao     = xn;  // overlay: xn dead after qkv_gemm

  size_t need = (size_t)(ws - (char*)d_ws);
  if (ws_size < need) return;

  rmsnorm_kernel   <<<ROWS, 256, 0, stream>>>(x, scale, xn);
  transpose_kernel <<<dim3(16,16,4), dim3(32,8), 0, stream>>>(Wq, Wk, Wv, Wo, wt_qkv, wo_t);
  rope_table_kernel<<<512, 256, 0, stream>>>(ctab, stab);
  qkv_gemm_kernel  <<<dim3(64,12), 256, 0, stream>>>(xn, wt_qkv, ctab, stab, qb, kb, vt);
  attn_kernel      <<<2048, 64, 0, stream>>>(qb, kb, vt, ao);
  out_gemm_kernel  <<<dim3(64,4), 256, 0, stream>>>(ao, wo_t, out);
}

// Round 3
// 214.670 us; speedup vs baseline: 1.4082x; 1.4082x over previous
//
#include <hip/hip_runtime.h>
#include <hip/hip_bf16.h>

typedef _Float16 f16;
typedef _Float16 f16x4 __attribute__((ext_vector_type(4)));
typedef _Float16 f16x8 __attribute__((ext_vector_type(8)));
typedef float f32x4 __attribute__((ext_vector_type(4)));

#define S_LEN 4096
#define DIM   512
#define NH    8
#define DH    64
#define BATCH 2
#define BHDIM (BATCH*NH)   // 16

// Q pre-scale: 1/sqrt(64) * log2(e)  (softmax done in exp2 domain)
#define QSCALE 0.18033688011112042f

__device__ __forceinline__ void gld16(const f16* g, f16* l) {
#if __has_builtin(__builtin_amdgcn_global_load_lds)
  __builtin_amdgcn_global_load_lds((const __attribute__((address_space(1))) void*)g,
                                   (__attribute__((address_space(3))) void*)l, 16, 0, 0);
#else
  *(f16x8*)l = *(const f16x8*)g;
#endif
}

__device__ __forceinline__ float fexp2(float x) {
#if __has_builtin(__builtin_amdgcn_exp2f)
  return __builtin_amdgcn_exp2f(x);
#else
  return exp2f(x);
#endif
}

// ---------------- RMSNorm: x[8192,512] f32 -> xn f16 ----------------
__global__ __launch_bounds__(256) void rmsnorm_kernel(
    const float* __restrict__ x, const float* __restrict__ scale,
    f16* __restrict__ xn) {
  int row = blockIdx.x;
  int tid = threadIdx.x;
  const float* xr = x + (size_t)row * DIM;
  float2 v = *(const float2*)(xr + tid*2);
  float ss = v.x*v.x + v.y*v.y;
  #pragma unroll
  for (int off = 32; off > 0; off >>= 1) ss += __shfl_down(ss, off);
  __shared__ float red[4];
  if ((tid & 63) == 0) red[tid >> 6] = ss;
  __syncthreads();
  float tot = red[0] + red[1] + red[2] + red[3];
  float inv = rsqrtf(tot * (1.0f/DIM) + 1e-6f);
  float2 s = *(const float2*)(scale + tid*2);
  xn[(size_t)row*DIM + tid*2+0] = (f16)(v.x*inv*s.x);
  xn[(size_t)row*DIM + tid*2+1] = (f16)(v.y*inv*s.y);
}

// ------------- Transpose+convert weights: W[k][n] f32 -> Wt[n][k] f16 -------------
__global__ void transpose_kernel(const float* __restrict__ Wq,
                                 const float* __restrict__ Wk,
                                 const float* __restrict__ Wv,
                                 const float* __restrict__ Wo,
                                 f16* __restrict__ wt_qkv, f16* __restrict__ wo_t) {
  __shared__ f16 tile[32][33];
  int mat = blockIdx.z;
  const float* src = (mat == 0) ? Wq : (mat == 1) ? Wk : (mat == 2) ? Wv : Wo;
  f16* dst = (mat < 3) ? (wt_qkv + (size_t)mat*DIM*DIM) : wo_t;
  int k0 = blockIdx.y * 32, n0 = blockIdx.x * 32;
  int tx = threadIdx.x, ty = threadIdx.y;  // (32, 8)
  #pragma unroll
  for (int i = 0; i < 32; i += 8)
    tile[ty+i][tx] = (f16)src[(size_t)(k0+ty+i)*DIM + n0+tx];
  __syncthreads();
  #pragma unroll
  for (int i = 0; i < 32; i += 8)
    dst[(size_t)(n0+ty+i)*DIM + k0+tx] = tile[tx][ty+i];
}

// ------------- RoPE cos/sin tables: [4096][32] f32 -------------
__global__ __launch_bounds__(256) void rope_table_kernel(float* __restrict__ ctab,
                                                         float* __restrict__ stab) {
  int idx = blockIdx.x*256 + threadIdx.x;   // 0..131071
  int t = idx >> 5, d = idx & 31;
  float theta = exp2f(-(float)d * (19.931568569324174f / 32.0f));
  float sv, cv;
  sincosf((float)t * theta, &sv, &cv);
  ctab[idx] = cv; stab[idx] = sv;
}

// ------------- m97-style 128x128 GEMM core: C = A[M,512] * Bt[N,512]^T -------------
__device__ __forceinline__ void gemm128_acc(
    const f16* __restrict__ A, const f16* __restrict__ Bt,
    int m0, int n0, f16* As, f16* Bs, f32x4 (&acc)[4][4]) {
  const int tid = threadIdx.x;
  const int wave = tid >> 6, lane = tid & 63;
  const int l16 = lane & 15, quad = lane >> 4;
  const int mrow = (wave & 1) * 64, ncol = (wave >> 1) * 64;
  const int srow = tid >> 3;                    // 0..31
  const int gc = (tid & 7) ^ ((tid >> 3) & 7);  // swizzled source chunk

  for (int k0 = 0; k0 < DIM; k0 += 64) {
    if (k0) __syncthreads();
    #pragma unroll
    for (int i = 0; i < 4; i++) {
      gld16(A  + (size_t)(m0 + i*32 + srow)*DIM + k0 + gc*8, As + i*2048 + tid*8);
      gld16(Bt + (size_t)(n0 + i*32 + srow)*DIM + k0 + gc*8, Bs + i*2048 + tid*8);
    }
    __syncthreads();
    #pragma unroll
    for (int kc = 0; kc < 2; kc++) {
      f16x8 a[4], b[4];
      #pragma unroll
      for (int mt = 0; mt < 4; mt++) {
        int row = mrow + mt*16 + l16;
        a[mt] = *(const f16x8*)(As + row*64 + (((quad + 4*kc) ^ (l16 & 7)) * 8));
      }
      #pragma unroll
      for (int nt = 0; nt < 4; nt++) {
        int row = ncol + nt*16 + l16;
        b[nt] = *(const f16x8*)(Bs + row*64 + (((quad + 4*kc) ^ (l16 & 7)) * 8));
      }
      #pragma unroll
      for (int mt = 0; mt < 4; mt++)
        #pragma unroll
        for (int nt = 0; nt < 4; nt++)
          acc[mt][nt] = __builtin_amdgcn_mfma_f32_16x16x32_f16(a[mt], b[nt], acc[mt][nt], 0, 0, 0);
    }
  }
}

// ------------- QKV GEMM + table-RoPE + Q prescale -------------
__global__ __launch_bounds__(256) void qkv_gemm_kernel(
    const f16* __restrict__ xn, const f16* __restrict__ wt,
    const float* __restrict__ ctab, const float* __restrict__ stab,
    f16* __restrict__ qbuf, f16* __restrict__ kbuf, f16* __restrict__ vt) {
  __shared__ __align__(16) f16 As[128*64], Bs[128*64];
  int m0 = blockIdx.x * 128, n0 = blockIdx.y * 128;
  f32x4 acc[4][4] = {};
  gemm128_acc(xn, wt, m0, n0, As, Bs, acc);

  const int tid = threadIdx.x;
  const int wave = tid >> 6, lane = tid & 63;
  const int l16 = lane & 15, quad = lane >> 4;
  int ncol = n0 + (wave >> 1) * 64;      // head-aligned
  int which = ncol >> 9;                 // 0=q 1=k 2=v (wave-uniform)
  int head = (ncol >> 6) & 7;
  int mbase = m0 + (wave & 1) * 64;

  if (which <= 1) {                      // fused RoPE from tables
    #pragma unroll
    for (int mt = 0; mt < 4; mt++)
      #pragma unroll
      for (int nt = 0; nt < 2; nt++) {
        int d = nt*16 + l16;
        #pragma unroll
        for (int r = 0; r < 4; r++) {
          int t = (mbase + mt*16 + quad*4 + r) & 4095;
          float cv = ctab[t*32 + d], sv = stab[t*32 + d];
          float x1 = acc[mt][nt][r], x2 = acc[mt][nt+2][r];
          acc[mt][nt][r]   = x1*cv - x2*sv;
          acc[mt][nt+2][r] = x1*sv + x2*cv;
        }
      }
  }
  if (which < 2) {
    float osc = (which == 0) ? QSCALE : 1.0f;
    f16* dst = which ? kbuf : qbuf;
    #pragma unroll
    for (int mt = 0; mt < 4; mt++)
      #pragma unroll
      for (int nt = 0; nt < 4; nt++)
        #pragma unroll
        for (int r = 0; r < 4; r++) {
          int m = mbase + mt*16 + quad*4 + r;
          int b = m >> 12, t = m & 4095;
          dst[(((size_t)(b*NH + head))*S_LEN + t)*DH + nt*16 + l16] = (f16)(acc[mt][nt][r]*osc);
        }
  } else {                               // V transposed, pack 4 consecutive tokens
    #pragma unroll
    for (int mt = 0; mt < 4; mt++)
      #pragma unroll
      for (int nt = 0; nt < 4; nt++) {
        int m = mbase + mt*16 + quad*4;
        int b = m >> 12, t = m & 4095;
        int d = nt*16 + l16;
        f16x4 v4 = {(f16)acc[mt][nt][0], (f16)acc[mt][nt][1],
                    (f16)acc[mt][nt][2], (f16)acc[mt][nt][3]};
        *(f16x4*)(vt + ((size_t)((b*NH + head)*DH + d))*S_LEN + t) = v4;
      }
  }
}

// ------------- Flash attention (causal), 2-wave blocks, async dbuf staging -------------
// 1024 blocks x 128 threads. Block = 64 q-rows (2 waves x 32). KVBLK=64,
// K/V double-buffered in LDS via global_load_lds (async, 1 barrier/tile).
// LDS 40KB -> 4 blocks/CU co-resident. bid&7 == bh&7 (XCD/L2 locality).
// qhalf(g) boustrophedon: per-CU tile sums are exactly equal, heavy first.
__global__ __launch_bounds__(128, 2) void attn_kernel(
    const f16* __restrict__ qbuf, const f16* __restrict__ kbuf,
    const f16* __restrict__ vtb, f16* __restrict__ ao) {
  int bid = blockIdx.x;                  // 0..1023
  int bh  = bid & 15;
  int g   = bid >> 4;                    // 0..63
  int r4 = g >> 4, j = g & 15;
  int qhalf = (r4 == 0) ? (63 - j) : (r4 == 1) ? (32 + j)
            : (r4 == 2) ? (31 - j) : j;  // 64-row block index, 0..63

  int tid = threadIdx.x;
  int wave = tid >> 6, lane = tid & 63;
  int l16 = lane & 15, quad = lane >> 4;

  const f16* Q = qbuf + (size_t)bh*S_LEN*DH;
  const f16* K = kbuf + (size_t)bh*S_LEN*DH;
  const f16* V = vtb  + (size_t)bh*DH*S_LEN;   // [dh][s]

  int rw = qhalf*64 + wave*32;           // wave's 32 q-rows
  int ntiles = qhalf + 1;                // 64-key tiles
  int ntl = 2*wave + 2;                  // live S^T frags on diagonal tile (uniform)
  int kcl = wave + 1;                    // live PV key-blocks on diagonal tile (uniform)

  // Q fragments (B-operand of S^T = K Q^T)
  f16x8 qa[2][2];
  #pragma unroll
  for (int mf = 0; mf < 2; mf++) {
    const f16* qrow = Q + (size_t)(rw + mf*16 + l16)*DH + quad*8;
    qa[mf][0] = *(const f16x8*)(qrow);
    qa[mf][1] = *(const f16x8*)(qrow + 32);
  }

  f32x4 o[2][4] = {};                    // O C-layout [qrow=quad*4+r][dh=dnt*16+l16]
  float m_i[2] = {-1e30f, -1e30f};       // per-lane state for qrow = l16 (replicated over quads)
  float l_i[2] = {0.f, 0.f};

  // K [2 bufs][64 kv][64 dh], V [2 bufs][64 dh][64 kv], P [2 waves][2 mf][16][64]
  __shared__ __align__(16) f16 kt[2*4096];
  __shared__ __align__(16) f16 vs[2*4096];
  __shared__ __align__(16) f16 pls[2*2048];

  const int gcs = (tid & 7) ^ ((tid >> 3) & 7);  // swizzled source chunk
  const int srow = tid >> 3;                     // 0..15

  // async stage of one 64-key tile into buffer `buf` (8 x gld16 per thread)
  #define STAGE(buf, kv)                                                        \
    do {                                                                        \
      f16* ktb = kt + (buf)*4096;                                               \
      f16* vsb = vs + (buf)*4096;                                               \
      _Pragma("unroll")                                                         \
      for (int n = 0; n < 4; n++) {                                             \
        gld16(K + (size_t)((kv) + n*16 + srow)*DH + gcs*8, ktb + n*1024 + tid*8);\
        gld16(V + (size_t)(n*16 + srow)*S_LEN + (kv) + gcs*8, vsb + n*1024 + tid*8);\
      }                                                                         \
    } while (0)

  STAGE(0, 0);
  __syncthreads();                       // drains vmcnt -> tile 0 staged

  for (int it = 0; it < ntiles; ++it) {
    int kv0 = it * 64;
    int cur = it & 1;
    bool last = (it == ntiles - 1);
    if (!last) STAGE(cur ^ 1, kv0 + 64); // async prefetch next tile

    const f16* ktc = kt + cur*4096;
    const f16* vsc = vs + cur*4096;

    // ---- S^T = K Q^T : C-layout row=key_local quad*4+r, col=qrow_local l16 ----
    f32x4 st[2][4];
    #pragma unroll
    for (int nt = 0; nt < 4; nt++) {
      if (!(last && nt >= ntl)) {
        int row = nt*16 + l16;
        f16x8 kf0 = *(const f16x8*)(ktc + row*64 + (((quad)     ^ (row & 7))*8));
        f16x8 kf1 = *(const f16x8*)(ktc + row*64 + (((quad + 4) ^ (row & 7))*8));
        f32x4 z0 = {}, z1 = {};
        z0 = __builtin_amdgcn_mfma_f32_16x16x32_f16(kf0, qa[0][0], z0, 0, 0, 0);
        z1 = __builtin_amdgcn_mfma_f32_16x16x32_f16(kf0, qa[1][0], z1, 0, 0, 0);
        st[0][nt] = __builtin_amdgcn_mfma_f32_16x16x32_f16(kf1, qa[0][1], z0, 0, 0, 0);
        st[1][nt] = __builtin_amdgcn_mfma_f32_16x16x32_f16(kf1, qa[1][1], z1, 0, 0, 0);
      }
    }

    #pragma unroll
    for (int mf = 0; mf < 2; mf++) {
      int qrow = rw + mf*16 + l16;
      float rmx = -1e30f;
      if (last) {                        // diagonal tile: causal mask (live frags only)
        #pragma unroll
        for (int nt = 0; nt < 4; nt++) {
          if (nt >= ntl) continue;
          int kbase = kv0 + nt*16 + quad*4;
          #pragma unroll
          for (int r = 0; r < 4; r++) {
            float v = st[mf][nt][r];
            if (kbase + r > qrow) v = -1e30f;
            st[mf][nt][r] = v;
            rmx = fmaxf(rmx, v);
          }
        }
      } else {
        #pragma unroll
        for (int nt = 0; nt < 4; nt++)
          #pragma unroll
          for (int r = 0; r < 4; r++) rmx = fmaxf(rmx, st[mf][nt][r]);
      }
      rmx = fmaxf(rmx, __shfl_xor(rmx, 16));
      rmx = fmaxf(rmx, __shfl_xor(rmx, 32));
      // defer-max (T13): skip O-rescale while running max grows < THR=8
      if (!__all(rmx <= m_i[mf] + 8.0f)) {
        float mnew = fmaxf(m_i[mf], rmx);
        float alpha = fexp2(m_i[mf] - mnew);
        m_i[mf] = mnew;
        float al[4];
        #pragma unroll
        for (int r = 0; r < 4; r++) al[r] = __shfl(alpha, quad*4 + r);
        #pragma unroll
        for (int dnt = 0; dnt < 4; dnt++)
          #pragma unroll
          for (int r = 0; r < 4; r++) o[mf][dnt][r] *= al[r];
        l_i[mf] *= alpha;
      }
      float mref = m_i[mf];
      // P = exp2(st - mref) (bounded by 2^8), pack f16x4, store to pls[wave][mf]
      float rs = 0.f;
      f16* plw = pls + wave*2048 + mf*1024 + l16*64;
      #pragma unroll
      for (int nt = 0; nt < 4; nt++) {
        if (last && nt >= ntl) continue;
        f16x4 p4;
        #pragma unroll
        for (int r = 0; r < 4; r++) {
          float p = fexp2(st[mf][nt][r] - mref);
          rs += p;
          p4[r] = (f16)p;
        }
        int cw = nt*2 + (quad >> 1);
        *(f16x4*)(plw + ((cw ^ (l16 & 7))*8) + (quad & 1)*4) = p4;
      }
      rs += __shfl_xor(rs, 16);
      rs += __shfl_xor(rs, 32);
      l_i[mf] += rs;
    }

    // ---- PV: single V pass, both mf halves per fragment ----
    #pragma unroll
    for (int kc = 0; kc < 2; kc++) {
      if (last && kc >= kcl) continue;
      int cp = ((kc*4 + quad) ^ (l16 & 7))*8;
      f16x8 pa0 = *(const f16x8*)(pls + wave*2048 +        l16*64 + cp);
      f16x8 pa1 = *(const f16x8*)(pls + wave*2048 + 1024 + l16*64 + cp);
      #pragma unroll
      for (int dnt = 0; dnt < 4; dnt++) {
        int vrow2 = dnt*16 + l16;
        f16x8 vf = *(const f16x8*)(vsc + vrow2*64 + (((kc*4 + quad) ^ (vrow2 & 7))*8));
        o[0][dnt] = __builtin_amdgcn_mfma_f32_16x16x32_f16(pa0, vf, o[0][dnt], 0, 0, 0);
        o[1][dnt] = __builtin_amdgcn_mfma_f32_16x16x32_f16(pa1, vf, o[1][dnt], 0, 0, 0);
      }
    }

    __syncthreads();  // all waves done reading cur; staged loads (vmcnt) drained
  }
  #undef STAGE

  // epilogue
  int b = bh >> 3, h = bh & 7;
  #pragma unroll
  for (int mf = 0; mf < 2; mf++) {
    float lr[4];
    #pragma unroll
    for (int r = 0; r < 4; r++) lr[r] = __shfl(l_i[mf], quad*4 + r);
    #pragma unroll
    for (int r = 0; r < 4; r++) {
      float invl = 1.0f / lr[r];
      int t = rw + mf*16 + quad*4 + r;
      size_t rowoff = ((size_t)(b*S_LEN + t))*DIM + h*DH;
      #pragma unroll
      for (int dnt = 0; dnt < 4; dnt++)
        ao[rowoff + dnt*16 + l16] = (f16)(o[mf][dnt][r]*invl);
    }
  }
}

// ------------- Output GEMM: ao[8192,512] @ Wo -> out f32 -------------
__global__ __launch_bounds__(256) void out_gemm_kernel(
    const f16* __restrict__ ao, const f16* __restrict__ wot,
    float* __restrict__ out) {
  __shared__ __align__(16) f16 As[128*64], Bs[128*64];
  int m0 = blockIdx.x * 128, n0 = blockIdx.y * 128;
  f32x4 acc[4][4] = {};
  gemm128_acc(ao, wot, m0, n0, As, Bs, acc);

  const int tid = threadIdx.x;
  const int wave = tid >> 6, lane = tid & 63;
  const int l16 = lane & 15, quad = lane >> 4;
  int ncol = n0 + (wave >> 1) * 64;
  int mbase = m0 + (wave & 1) * 64;
  #pragma unroll
  for (int mt = 0; mt < 4; mt++)
    #pragma unroll
    for (int nt = 0; nt < 4; nt++)
      #pragma unroll
      for (int r = 0; r < 4; r++)
        out[(size_t)(mbase + mt*16 + quad*4 + r)*DIM + ncol + nt*16 + l16] = acc[mt][nt][r];
}

extern "C" void kernel_launch(void* const* d_in, const int* in_sizes, int n_in,
                              void* d_out, int out_size, void* d_ws, size_t ws_size,
                              hipStream_t stream) {
  const float* x     = (const float*)d_in[0];
  const float* scale = (const float*)d_in[1];
  const float* Wq    = (const float*)d_in[2];
  const float* Wk    = (const float*)d_in[3];
  const float* Wv    = (const float*)d_in[4];
  const float* Wo    = (const float*)d_in[5];
  float* out = (float*)d_out;

  const size_t ROWS = (size_t)BATCH * S_LEN;   // 8192
  char* ws = (char*)d_ws;
  f16* xn     = (f16*)ws;  ws += ROWS * DIM * sizeof(f16);            // 8 MB (reused as ao)
  f16* wt_qkv = (f16*)ws;  ws += (size_t)3 * DIM * DIM * sizeof(f16); // 1.5 MB
  f16* wo_t   = (f16*)ws;  ws += (size_t)DIM * DIM * sizeof(f16);     // 0.5 MB
  f16* qb     = (f16*)ws;  ws += (size_t)BHDIM * S_LEN * DH * sizeof(f16); // 8 MB
  f16* kb     = (f16*)ws;  ws += (size_t)BHDIM * S_LEN * DH * sizeof(f16); // 8 MB
  f16* vt     = (f16*)ws;  ws += (size_t)BHDIM * S_LEN * DH * sizeof(f16); // 8 MB
  float* ctab = (float*)ws; ws += (size_t)S_LEN * 32 * sizeof(float);  // 0.5 MB
  float* stab = (float*)ws; ws += (size_t)S_LEN * 32 * sizeof(float);  // 0.5 MB
  f16* ao     = xn;  // overlay: xn dead after qkv_gemm

  size_t need = (size_t)(ws - (char*)d_ws);
  if (ws_size < need) return;

  rmsnorm_kernel   <<<ROWS, 256, 0, stream>>>(x, scale, xn);
  transpose_kernel <<<dim3(16,16,4), dim3(32,8), 0, stream>>>(Wq, Wk, Wv, Wo, wt_qkv, wo_t);
  rope_table_kernel<<<512, 256, 0, stream>>>(ctab, stab);
  qkv_gemm_kernel  <<<dim3(64,12), 256, 0, stream>>>(xn, wt_qkv, ctab, stab, qb, kb, vt);
  attn_kernel      <<<1024, 128, 0, stream>>>(qb, kb, vt, ao);
  out_gemm_kernel  <<<dim3(64,4), 256, 0, stream>>>(ao, wo_t, out);
}

// Round 4
// 210.957 us; speedup vs baseline: 1.4330x; 1.0176x over previous
//
#include <hip/hip_runtime.h>
#include <hip/hip_bf16.h>

typedef _Float16 f16;
typedef _Float16 f16x4 __attribute__((ext_vector_type(4)));
typedef _Float16 f16x8 __attribute__((ext_vector_type(8)));
typedef float f32x4 __attribute__((ext_vector_type(4)));

#define S_LEN 4096
#define DIM   512
#define NH    8
#define DH    64
#define BATCH 2
#define BHDIM (BATCH*NH)   // 16

// Q pre-scale: 1/sqrt(64) * log2(e)  (softmax done in exp2 domain)
#define QSCALE 0.18033688011112042f

__device__ __forceinline__ void gld16(const f16* g, f16* l) {
#if __has_builtin(__builtin_amdgcn_global_load_lds)
  __builtin_amdgcn_global_load_lds((const __attribute__((address_space(1))) void*)g,
                                   (__attribute__((address_space(3))) void*)l, 16, 0, 0);
#else
  *(f16x8*)l = *(const f16x8*)g;
#endif
}

__device__ __forceinline__ float fexp2(float x) {
#if __has_builtin(__builtin_amdgcn_exp2f)
  return __builtin_amdgcn_exp2f(x);
#else
  return exp2f(x);
#endif
}

// ---------------- RMSNorm: x[8192,512] f32 -> xn f16 ----------------
__global__ __launch_bounds__(256) void rmsnorm_kernel(
    const float* __restrict__ x, const float* __restrict__ scale,
    f16* __restrict__ xn) {
  int row = blockIdx.x;
  int tid = threadIdx.x;
  const float* xr = x + (size_t)row * DIM;
  float2 v = *(const float2*)(xr + tid*2);
  float ss = v.x*v.x + v.y*v.y;
  #pragma unroll
  for (int off = 32; off > 0; off >>= 1) ss += __shfl_down(ss, off);
  __shared__ float red[4];
  if ((tid & 63) == 0) red[tid >> 6] = ss;
  __syncthreads();
  float tot = red[0] + red[1] + red[2] + red[3];
  float inv = rsqrtf(tot * (1.0f/DIM) + 1e-6f);
  float2 s = *(const float2*)(scale + tid*2);
  xn[(size_t)row*DIM + tid*2+0] = (f16)(v.x*inv*s.x);
  xn[(size_t)row*DIM + tid*2+1] = (f16)(v.y*inv*s.y);
}

// ------------- Transpose+convert weights: W[k][n] f32 -> Wt[n][k] f16 -------------
__global__ void transpose_kernel(const float* __restrict__ Wq,
                                 const float* __restrict__ Wk,
                                 const float* __restrict__ Wv,
                                 const float* __restrict__ Wo,
                                 f16* __restrict__ wt_qkv, f16* __restrict__ wo_t) {
  __shared__ f16 tile[32][33];
  int mat = blockIdx.z;
  const float* src = (mat == 0) ? Wq : (mat == 1) ? Wk : (mat == 2) ? Wv : Wo;
  f16* dst = (mat < 3) ? (wt_qkv + (size_t)mat*DIM*DIM) : wo_t;
  int k0 = blockIdx.y * 32, n0 = blockIdx.x * 32;
  int tx = threadIdx.x, ty = threadIdx.y;  // (32, 8)
  #pragma unroll
  for (int i = 0; i < 32; i += 8)
    tile[ty+i][tx] = (f16)src[(size_t)(k0+ty+i)*DIM + n0+tx];
  __syncthreads();
  #pragma unroll
  for (int i = 0; i < 32; i += 8)
    dst[(size_t)(n0+ty+i)*DIM + k0+tx] = tile[tx][ty+i];
}

// ------------- RoPE cos/sin tables: [4096][32] f32 -------------
__global__ __launch_bounds__(256) void rope_table_kernel(float* __restrict__ ctab,
                                                         float* __restrict__ stab) {
  int idx = blockIdx.x*256 + threadIdx.x;   // 0..131071
  int t = idx >> 5, d = idx & 31;
  float theta = exp2f(-(float)d * (19.931568569324174f / 32.0f));
  float sv, cv;
  sincosf((float)t * theta, &sv, &cv);
  ctab[idx] = cv; stab[idx] = sv;
}

// ------------- m97-style 128x128 GEMM core: C = A[M,512] * Bt[N,512]^T -------------
__device__ __forceinline__ void gemm128_acc(
    const f16* __restrict__ A, const f16* __restrict__ Bt,
    int m0, int n0, f16* As, f16* Bs, f32x4 (&acc)[4][4]) {
  const int tid = threadIdx.x;
  const int wave = tid >> 6, lane = tid & 63;
  const int l16 = lane & 15, quad = lane >> 4;
  const int mrow = (wave & 1) * 64, ncol = (wave >> 1) * 64;
  const int srow = tid >> 3;                    // 0..31
  const int gc = (tid & 7) ^ ((tid >> 3) & 7);  // swizzled source chunk

  for (int k0 = 0; k0 < DIM; k0 += 64) {
    if (k0) __syncthreads();
    #pragma unroll
    for (int i = 0; i < 4; i++) {
      gld16(A  + (size_t)(m0 + i*32 + srow)*DIM + k0 + gc*8, As + i*2048 + tid*8);
      gld16(Bt + (size_t)(n0 + i*32 + srow)*DIM + k0 + gc*8, Bs + i*2048 + tid*8);
    }
    __syncthreads();
    #pragma unroll
    for (int kc = 0; kc < 2; kc++) {
      f16x8 a[4], b[4];
      #pragma unroll
      for (int mt = 0; mt < 4; mt++) {
        int row = mrow + mt*16 + l16;
        a[mt] = *(const f16x8*)(As + row*64 + (((quad + 4*kc) ^ (l16 & 7)) * 8));
      }
      #pragma unroll
      for (int nt = 0; nt < 4; nt++) {
        int row = ncol + nt*16 + l16;
        b[nt] = *(const f16x8*)(Bs + row*64 + (((quad + 4*kc) ^ (l16 & 7)) * 8));
      }
      #pragma unroll
      for (int mt = 0; mt < 4; mt++)
        #pragma unroll
        for (int nt = 0; nt < 4; nt++)
          acc[mt][nt] = __builtin_amdgcn_mfma_f32_16x16x32_f16(a[mt], b[nt], acc[mt][nt], 0, 0, 0);
    }
  }
}

// ------------- QKV GEMM + table-RoPE + Q prescale -------------
__global__ __launch_bounds__(256) void qkv_gemm_kernel(
    const f16* __restrict__ xn, const f16* __restrict__ wt,
    const float* __restrict__ ctab, const float* __restrict__ stab,
    f16* __restrict__ qbuf, f16* __restrict__ kbuf, f16* __restrict__ vt) {
  __shared__ __align__(16) f16 As[128*64], Bs[128*64];
  int m0 = blockIdx.x * 128, n0 = blockIdx.y * 128;
  f32x4 acc[4][4] = {};
  gemm128_acc(xn, wt, m0, n0, As, Bs, acc);

  const int tid = threadIdx.x;
  const int wave = tid >> 6, lane = tid & 63;
  const int l16 = lane & 15, quad = lane >> 4;
  int ncol = n0 + (wave >> 1) * 64;      // head-aligned
  int which = ncol >> 9;                 // 0=q 1=k 2=v (wave-uniform)
  int head = (ncol >> 6) & 7;
  int mbase = m0 + (wave & 1) * 64;

  if (which <= 1) {                      // fused RoPE from tables
    #pragma unroll
    for (int mt = 0; mt < 4; mt++)
      #pragma unroll
      for (int nt = 0; nt < 2; nt++) {
        int d = nt*16 + l16;
        #pragma unroll
        for (int r = 0; r < 4; r++) {
          int t = (mbase + mt*16 + quad*4 + r) & 4095;
          float cv = ctab[t*32 + d], sv = stab[t*32 + d];
          float x1 = acc[mt][nt][r], x2 = acc[mt][nt+2][r];
          acc[mt][nt][r]   = x1*cv - x2*sv;
          acc[mt][nt+2][r] = x1*sv + x2*cv;
        }
      }
  }
  if (which < 2) {
    float osc = (which == 0) ? QSCALE : 1.0f;
    f16* dst = which ? kbuf : qbuf;
    #pragma unroll
    for (int mt = 0; mt < 4; mt++)
      #pragma unroll
      for (int nt = 0; nt < 4; nt++)
        #pragma unroll
        for (int r = 0; r < 4; r++) {
          int m = mbase + mt*16 + quad*4 + r;
          int b = m >> 12, t = m & 4095;
          dst[(((size_t)(b*NH + head))*S_LEN + t)*DH + nt*16 + l16] = (f16)(acc[mt][nt][r]*osc);
        }
  } else {                               // V transposed, pack 4 consecutive tokens
    #pragma unroll
    for (int mt = 0; mt < 4; mt++)
      #pragma unroll
      for (int nt = 0; nt < 4; nt++) {
        int m = mbase + mt*16 + quad*4;
        int b = m >> 12, t = m & 4095;
        int d = nt*16 + l16;
        f16x4 v4 = {(f16)acc[mt][nt][0], (f16)acc[mt][nt][1],
                    (f16)acc[mt][nt][2], (f16)acc[mt][nt][3]};
        *(f16x4*)(vt + ((size_t)((b*NH + head)*DH + d))*S_LEN + t) = v4;
      }
  }
}

// ------------- Flash attention (causal), paired q-bands, equal-work blocks -------------
// 1024 blocks x 128 threads. Block = band pair (p, 127-p), bands of 32 q-rows;
// each wave handles 16 rows of each band. Tile work per block = 65 for EVERY p
// (makespan-balanced; no scheduling table needed). KVBLK=64, K/V double-buffered
// via global_load_lds, 1 barrier/tile. LDS 40KB -> 4 blocks/CU. bid&7==bh&7 (XCD).
__global__ __launch_bounds__(128, 2) void attn_kernel(
    const f16* __restrict__ qbuf, const f16* __restrict__ kbuf,
    const f16* __restrict__ vtb, f16* __restrict__ ao) {
  int bid = blockIdx.x;                  // 0..1023
  int bh  = bid & 15;
  int p   = bid >> 4;                    // pair index 0..63

  int tid = threadIdx.x;
  int wave = tid >> 6, lane = tid & 63;
  int l16 = lane & 15, quad = lane >> 4;

  const f16* Q = qbuf + (size_t)bh*S_LEN*DH;
  const f16* K = kbuf + (size_t)bh*S_LEN*DH;
  const f16* V = vtb  + (size_t)bh*DH*S_LEN;   // [dh][s]

  // bi=0: heavy band 127-p, bi=1: light band p (32 q-rows each; wave owns 16)
  int bandv[2] = {127 - p, p};
  int tcnt[2]  = {((127 - p) >> 1) + 1, (p >> 1) + 1};   // sums to 65 for all p
  int rbase[2] = {bandv[0]*32 + wave*16, bandv[1]*32 + wave*16};

  // Q fragments (B-operand of S^T = K Q^T), per band
  f16x8 qa[2][2];
  #pragma unroll
  for (int bi = 0; bi < 2; bi++) {
    const f16* qrow = Q + (size_t)(rbase[bi] + l16)*DH + quad*8;
    qa[bi][0] = *(const f16x8*)(qrow);
    qa[bi][1] = *(const f16x8*)(qrow + 32);
  }

  f32x4 o[2][4] = {};                    // per band: O C-layout [qrow=quad*4+r][dh=dnt*16+l16]
  float m_i[2] = {-1e30f, -1e30f};
  float l_i[2] = {0.f, 0.f};

  // K [2 bufs][64 kv][64 dh], V [2 bufs][64 dh][64 kv], P [2 waves][2 bands][16][64]
  __shared__ __align__(16) f16 kt[2*4096];
  __shared__ __align__(16) f16 vs[2*4096];
  __shared__ __align__(16) f16 pls[4096];

  const int gcs = (tid & 7) ^ ((tid >> 3) & 7);  // swizzled source chunk
  const int srow = tid >> 3;                     // 0..15

  #define STAGE(buf, kv)                                                        \
    do {                                                                        \
      f16* ktb = kt + (buf)*4096;                                               \
      f16* vsb = vs + (buf)*4096;                                               \
      _Pragma("unroll")                                                         \
      for (int n = 0; n < 4; n++) {                                             \
        gld16(K + (size_t)((kv) + n*16 + srow)*DH + gcs*8, ktb + n*1024 + tid*8);\
        gld16(V + (size_t)(n*16 + srow)*S_LEN + (kv) + gcs*8, vsb + n*1024 + tid*8);\
      }                                                                         \
    } while (0)

  STAGE(0, 0);
  __syncthreads();                       // drains vmcnt -> tile 0 staged

  int nth = tcnt[0];
  for (int it = 0; it < nth; ++it) {
    int kv0 = it * 64;
    int cur = it & 1;
    if (it + 1 < nth) STAGE(cur ^ 1, kv0 + 64);   // async prefetch next tile

    const f16* ktc = kt + cur*4096;
    const f16* vsc = vs + cur*4096;

    bool act1 = (it < tcnt[1]);
    bool dia[2] = {it == tcnt[0] - 1, it == tcnt[1] - 1};

    #pragma unroll
    for (int bi = 0; bi < 2; bi++) {
      if (bi == 1 && !act1) continue;
      bool diag = dia[bi];
      int ntl = diag ? ((bandv[bi] & 1) ? 4 : 2) : 4;   // live 16-key frags

      // ---- S^T = K Q^T : C-layout row=key_local quad*4+r, col=qrow_local l16 ----
      f32x4 st[4];
      #pragma unroll
      for (int nt = 0; nt < 4; nt++) {
        if (nt >= ntl) continue;
        int row = nt*16 + l16;
        f16x8 kf0 = *(const f16x8*)(ktc + row*64 + (((quad)     ^ (row & 7))*8));
        f16x8 kf1 = *(const f16x8*)(ktc + row*64 + (((quad + 4) ^ (row & 7))*8));
        f32x4 z = {};
        z = __builtin_amdgcn_mfma_f32_16x16x32_f16(kf0, qa[bi][0], z, 0, 0, 0);
        st[nt] = __builtin_amdgcn_mfma_f32_16x16x32_f16(kf1, qa[bi][1], z, 0, 0, 0);
      }

      // ---- softmax (per q-row l16, replicated over quads) ----
      int qglob = rbase[bi] + l16;
      float rmx = -1e30f;
      #pragma unroll
      for (int nt = 0; nt < 4; nt++) {
        if (nt >= ntl) continue;
        if (diag) {
          int kb = kv0 + nt*16 + quad*4;
          #pragma unroll
          for (int r = 0; r < 4; r++) {
            float v = st[nt][r];
            if (kb + r > qglob) v = -1e30f;
            st[nt][r] = v;
            rmx = fmaxf(rmx, v);
          }
        } else {
          #pragma unroll
          for (int r = 0; r < 4; r++) rmx = fmaxf(rmx, st[nt][r]);
        }
      }
      rmx = fmaxf(rmx, __shfl_xor(rmx, 16));
      rmx = fmaxf(rmx, __shfl_xor(rmx, 32));
      // defer-max (T13): skip O-rescale while running max grows < THR=8
      if (!__all(rmx <= m_i[bi] + 8.0f)) {
        float mnew = fmaxf(m_i[bi], rmx);
        float alpha = fexp2(m_i[bi] - mnew);
        m_i[bi] = mnew;
        float al[4];
        #pragma unroll
        for (int r = 0; r < 4; r++) al[r] = __shfl(alpha, quad*4 + r);
        #pragma unroll
        for (int dnt = 0; dnt < 4; dnt++)
          #pragma unroll
          for (int r = 0; r < 4; r++) o[bi][dnt][r] *= al[r];
        l_i[bi] *= alpha;
      }
      float mref = m_i[bi];
      // P = exp2(st - mref) (bounded by 2^8), pack f16x4, store to pls[wave][bi]
      float rs = 0.f;
      f16* plw = pls + wave*2048 + bi*1024 + l16*64;
      #pragma unroll
      for (int nt = 0; nt < 4; nt++) {
        if (nt >= ntl) continue;
        f16x4 p4;
        #pragma unroll
        for (int r = 0; r < 4; r++) {
          float pv = fexp2(st[nt][r] - mref);
          rs += pv;
          p4[r] = (f16)pv;
        }
        int cw = nt*2 + (quad >> 1);
        *(f16x4*)(plw + ((cw ^ (l16 & 7))*8) + (quad & 1)*4) = p4;
      }
      rs += __shfl_xor(rs, 16);
      rs += __shfl_xor(rs, 32);
      l_i[bi] += rs;
    }

    // ---- PV: both bands share each V fragment ----
    int kcl0 = dia[0] ? ((bandv[0] & 1) ? 2 : 1) : 2;
    int kcl1 = act1 ? (dia[1] ? ((bandv[1] & 1) ? 2 : 1) : 2) : 0;
    #pragma unroll
    for (int kc = 0; kc < 2; kc++) {
      bool lv0 = (kc < kcl0), lv1 = (kc < kcl1);
      if (!lv0 && !lv1) continue;
      int cp = ((kc*4 + quad) ^ (l16 & 7))*8;
      f16x8 pa0, pa1;
      if (lv0) pa0 = *(const f16x8*)(pls + wave*2048 +        l16*64 + cp);
      if (lv1) pa1 = *(const f16x8*)(pls + wave*2048 + 1024 + l16*64 + cp);
      #pragma unroll
      for (int dnt = 0; dnt < 4; dnt++) {
        int vr = dnt*16 + l16;
        f16x8 vf = *(const f16x8*)(vsc + vr*64 + (((kc*4 + quad) ^ (vr & 7))*8));
        if (lv0) o[0][dnt] = __builtin_amdgcn_mfma_f32_16x16x32_f16(pa0, vf, o[0][dnt], 0, 0, 0);
        if (lv1) o[1][dnt] = __builtin_amdgcn_mfma_f32_16x16x32_f16(pa1, vf, o[1][dnt], 0, 0, 0);
      }
    }

    __syncthreads();  // all waves done reading cur; staged loads (vmcnt) drained
  }
  #undef STAGE

  // epilogue: two 16-row bands per wave
  int b = bh >> 3, h = bh & 7;
  #pragma unroll
  for (int bi = 0; bi < 2; bi++) {
    float lr[4];
    #pragma unroll
    for (int r = 0; r < 4; r++) lr[r] = __shfl(l_i[bi], quad*4 + r);
    #pragma unroll
    for (int r = 0; r < 4; r++) {
      float invl = 1.0f / lr[r];
      int t = rbase[bi] + quad*4 + r;
      size_t rowoff = ((size_t)(b*S_LEN + t))*DIM + h*DH;
      #pragma unroll
      for (int dnt = 0; dnt < 4; dnt++)
        ao[rowoff + dnt*16 + l16] = (f16)(o[bi][dnt][r]*invl);
    }
  }
}

// ------------- Output GEMM: ao[8192,512] @ Wo -> out f32 -------------
__global__ __launch_bounds__(256) void out_gemm_kernel(
    const f16* __restrict__ ao, const f16* __restrict__ wot,
    float* __restrict__ out) {
  __shared__ __align__(16) f16 As[128*64], Bs[128*64];
  int m0 = blockIdx.x * 128, n0 = blockIdx.y * 128;
  f32x4 acc[4][4] = {};
  gemm128_acc(ao, wot, m0, n0, As, Bs, acc);

  const int tid = threadIdx.x;
  const int wave = tid >> 6, lane = tid & 63;
  const int l16 = lane & 15, quad = lane >> 4;
  int ncol = n0 + (wave >> 1) * 64;
  int mbase = m0 + (wave & 1) * 64;
  #pragma unroll
  for (int mt = 0; mt < 4; mt++)
    #pragma unroll
    for (int nt = 0; nt < 4; nt++)
      #pragma unroll
      for (int r = 0; r < 4; r++)
        out[(size_t)(mbase + mt*16 + quad*4 + r)*DIM + ncol + nt*16 + l16] = acc[mt][nt][r];
}

extern "C" void kernel_launch(void* const* d_in, const int* in_sizes, int n_in,
                              void* d_out, int out_size, void* d_ws, size_t ws_size,
                              hipStream_t stream) {
  const float* x     = (const float*)d_in[0];
  const float* scale = (const float*)d_in[1];
  const float* Wq    = (const float*)d_in[2];
  const float* Wk    = (const float*)d_in[3];
  const float* Wv    = (const float*)d_in[4];
  const float* Wo    = (const float*)d_in[5];
  float* out = (float*)d_out;

  const size_t ROWS = (size_t)BATCH * S_LEN;   // 8192
  char* ws = (char*)d_ws;
  f16* xn     = (f16*)ws;  ws += ROWS * DIM * sizeof(f16);            // 8 MB (reused as ao)
  f16* wt_qkv = (f16*)ws;  ws += (size_t)3 * DIM * DIM * sizeof(f16); // 1.5 MB
  f16* wo_t   = (f16*)ws;  ws += (size_t)DIM * DIM * sizeof(f16);     // 0.5 MB
  f16* qb     = (f16*)ws;  ws += (size_t)BHDIM * S_LEN * DH * sizeof(f16); // 8 MB
  f16* kb     = (f16*)ws;  ws += (size_t)BHDIM * S_LEN * DH * sizeof(f16); // 8 MB
  f16* vt     = (f16*)ws;  ws += (size_t)BHDIM * S_LEN * DH * sizeof(f16); // 8 MB
  float* ctab = (float*)ws; ws += (size_t)S_LEN * 32 * sizeof(float);  // 0.5 MB
  float* stab = (float*)ws; ws += (size_t)S_LEN * 32 * sizeof(float);  // 0.5 MB
  f16* ao     = xn;  // overlay: xn dead after qkv_gemm

  size_t need = (size_t)(ws - (char*)d_ws);
  if (ws_size < need) return;

  rmsnorm_kernel   <<<ROWS, 256, 0, stream>>>(x, scale, xn);
  transpose_kernel <<<dim3(16,16,4), dim3(32,8), 0, stream>>>(Wq, Wk, Wv, Wo, wt_qkv, wo_t);
  rope_table_kernel<<<512, 256, 0, stream>>>(ctab, stab);
  qkv_gemm_kernel  <<<dim3(64,12), 256, 0, stream>>>(xn, wt_qkv, ctab, stab, qb, kb, vt);
  attn_kernel      <<<1024, 128, 0, stream>>>(qb, kb, vt, ao);
  out_gemm_kernel  <<<dim3(64,4), 256, 0, stream>>>(ao, wo_t, out);
}